// Round 1
// baseline (215.678 us; speedup 1.0000x reference)
//
#include <hip/hip_runtime.h>
#include <hip/hip_bf16.h>
#include <stdint.h>

#define N_BATCH 4096
#define D_DIM   1024
#define M_ROWS  8192                     // 2N
#define TINV    2.0f                     // 1/temperature
#define EXP_SCALE 2.8853900817779268f    // log2(e)/t  (t=0.5)
#define LN2 0.6931471805599453f

typedef __bf16 bf16x8 __attribute__((ext_vector_type(8)));
typedef float  f32x4  __attribute__((ext_vector_type(4)));

__device__ __forceinline__ void load_lds16(const __bf16* g, __bf16* l) {
    __builtin_amdgcn_global_load_lds(
        (const __attribute__((address_space(1))) void*)g,
        (__attribute__((address_space(3))) void*)l, 16, 0, 0);
}

// ---------------- kernel 1: L2-normalize rows, emit bf16 Z, zero denom -----
__global__ __launch_bounds__(256) void normalize_kernel(
    const float* __restrict__ emb_i, const float* __restrict__ emb_j,
    __bf16* __restrict__ zb, float* __restrict__ denom)
{
    int row = blockIdx.x;                          // 0..8191
    const float* src = (row < N_BATCH)
        ? (emb_i + (size_t)row * D_DIM)
        : (emb_j + (size_t)(row - N_BATCH) * D_DIM);
    float4 v = ((const float4*)src)[threadIdx.x];  // 256 thr x 4 = 1024
    float ss = v.x*v.x + v.y*v.y + v.z*v.z + v.w*v.w;
    #pragma unroll
    for (int m = 1; m < 64; m <<= 1) ss += __shfl_xor(ss, m, 64);
    __shared__ float red[4];
    int wv = threadIdx.x >> 6;
    if ((threadIdx.x & 63) == 0) red[wv] = ss;
    __syncthreads();
    float total = red[0] + red[1] + red[2] + red[3];
    float scale = 1.0f / fmaxf(sqrtf(total), 1e-12f);
    union { __bf16 h[4]; uint2 u; } cv;
    cv.h[0] = (__bf16)(v.x * scale);
    cv.h[1] = (__bf16)(v.y * scale);
    cv.h[2] = (__bf16)(v.z * scale);
    cv.h[3] = (__bf16)(v.w * scale);
    *(uint2*)(zb + (size_t)row * D_DIM + threadIdx.x * 4) = cv.u;
    if (threadIdx.x == 0) denom[row] = 0.0f;
}

// ---------------- kernel 2: positives, exact fp32 from raw inputs ----------
__global__ __launch_bounds__(256) void pos_kernel(
    const float* __restrict__ emb_i, const float* __restrict__ emb_j,
    float* __restrict__ pos)
{
    int i    = blockIdx.x * 4 + (threadIdx.x >> 6);  // one wave per pair
    int lane = threadIdx.x & 63;
    const float4* a = (const float4*)(emb_i + (size_t)i * D_DIM);
    const float4* b = (const float4*)(emb_j + (size_t)i * D_DIM);
    float dot = 0.f, ssa = 0.f, ssb = 0.f;
    #pragma unroll
    for (int it = 0; it < 4; ++it) {
        float4 va = a[lane + it * 64];
        float4 vb = b[lane + it * 64];
        dot += va.x*vb.x + va.y*vb.y + va.z*vb.z + va.w*vb.w;
        ssa += va.x*va.x + va.y*va.y + va.z*va.z + va.w*va.w;
        ssb += vb.x*vb.x + vb.y*vb.y + vb.z*vb.z + vb.w*vb.w;
    }
    #pragma unroll
    for (int m = 1; m < 64; m <<= 1) {
        dot += __shfl_xor(dot, m, 64);
        ssa += __shfl_xor(ssa, m, 64);
        ssb += __shfl_xor(ssb, m, 64);
    }
    if (lane == 0)
        pos[i] = dot / (fmaxf(sqrtf(ssa), 1e-12f) * fmaxf(sqrtf(ssb), 1e-12f));
}

// ---------------- kernel 3: fused sim = Z Z^T -> exp -> masked row sums ----
// 128x128 tile, BK=32, 16x16x32 bf16 MFMA, upper-triangular blocks only
// (symmetry: off-diag tile contributes row sums AND col sums).
__global__ __launch_bounds__(256) void simexp_kernel(
    const __bf16* __restrict__ Z, float* __restrict__ denom)
{
    int bx = blockIdx.x;        // col band
    int by = blockIdx.y;        // row band
    if (bx < by) return;        // lower triangle handled via symmetry
    int tile_m = by * 128, tile_n = bx * 128;

    __shared__ __align__(16) __bf16 As[128 * 32];
    __shared__ __align__(16) __bf16 Bs[128 * 32];

    int t    = threadIdx.x;
    int wv   = t >> 6;
    int lane = t & 63;
    int wave_m = (wv >> 1) * 64;
    int wave_n = (wv & 1) * 64;
    int quad = lane >> 4;
    int l15  = lane & 15;

    f32x4 acc[4][4] = {};

    // staging addresses: thread t loads 16B at row=t/4 (+64 for it=1), col=(t&3)*8
    int srow = t >> 2;
    int scol = (t & 3) * 8;
    const __bf16* gA = Z + (size_t)(tile_m + srow) * D_DIM + scol;
    const __bf16* gB = Z + (size_t)(tile_n + srow) * D_DIM + scol;
    __bf16* lA0 = As + wv * 512;         // wave-uniform LDS dst (lane*16B implied)
    __bf16* lA1 = As + 2048 + wv * 512;
    __bf16* lB0 = Bs + wv * 512;
    __bf16* lB1 = Bs + 2048 + wv * 512;

    for (int k0 = 0; k0 < D_DIM; k0 += 32) {
        __syncthreads();
        load_lds16(gA + k0,               lA0);
        load_lds16(gA + 64 * D_DIM + k0,  lA1);
        load_lds16(gB + k0,               lB0);
        load_lds16(gB + 64 * D_DIM + k0,  lB1);
        __syncthreads();

        bf16x8 af[4], bf[4];
        #pragma unroll
        for (int f = 0; f < 4; ++f) {
            af[f] = *(const bf16x8*)&As[(wave_m + f * 16 + l15) * 32 + quad * 8];
            bf[f] = *(const bf16x8*)&Bs[(wave_n + f * 16 + l15) * 32 + quad * 8];
        }
        #pragma unroll
        for (int fm = 0; fm < 4; ++fm)
            #pragma unroll
            for (int fn = 0; fn < 4; ++fn)
                acc[fm][fn] = __builtin_amdgcn_mfma_f32_16x16x32_bf16(
                    af[fm], bf[fn], acc[fm][fn], 0, 0, 0);
    }

    // epilogue: e = exp(sim/t) = exp2(sim * EXP_SCALE); mask diag; reduce
    bool diagblk = (bx == by);
    float rowsum[4][4];
    float colsum[4];
    #pragma unroll
    for (int fm = 0; fm < 4; ++fm)
        #pragma unroll
        for (int r = 0; r < 4; ++r) rowsum[fm][r] = 0.f;
    #pragma unroll
    for (int fn = 0; fn < 4; ++fn) colsum[fn] = 0.f;

    #pragma unroll
    for (int fm = 0; fm < 4; ++fm) {
        #pragma unroll
        for (int fn = 0; fn < 4; ++fn) {
            #pragma unroll
            for (int r = 0; r < 4; ++r) {
                float e = __builtin_amdgcn_exp2f(acc[fm][fn][r] * EXP_SCALE);
                if (diagblk) {
                    int lrow = wave_m + fm * 16 + quad * 4 + r;
                    int lcol = wave_n + fn * 16 + l15;
                    if (lrow == lcol) e = 0.f;   // mask self-similarity
                }
                rowsum[fm][r] += e;
                colsum[fn]    += e;
            }
        }
    }
    // row sums: reduce across the 16 lanes of each quad (cols), atomic per row
    #pragma unroll
    for (int fm = 0; fm < 4; ++fm) {
        #pragma unroll
        for (int r = 0; r < 4; ++r) {
            float s = rowsum[fm][r];
            s += __shfl_xor(s, 1, 64);
            s += __shfl_xor(s, 2, 64);
            s += __shfl_xor(s, 4, 64);
            s += __shfl_xor(s, 8, 64);
            if (l15 == 0)
                atomicAdd(&denom[tile_m + wave_m + fm * 16 + quad * 4 + r], s);
        }
    }
    // col sums (= symmetric rows in the other band): reduce across quads
    if (!diagblk) {
        #pragma unroll
        for (int fn = 0; fn < 4; ++fn) {
            float s = colsum[fn];
            s += __shfl_xor(s, 16, 64);
            s += __shfl_xor(s, 32, 64);
            if (quad == 0)
                atomicAdd(&denom[tile_n + wave_n + fn * 16 + l15], s);
        }
    }
}

// ---------------- kernel 4: loss = [sum log(denom) - (2/t) sum pos] / 2N ---
__global__ __launch_bounds__(256) void finalize_kernel(
    const float* __restrict__ denom, const float* __restrict__ pos,
    float* __restrict__ out)
{
    float a1 = 0.f, a2 = 0.f;
    for (int r = threadIdx.x; r < M_ROWS; r += 256)
        a1 += __builtin_amdgcn_logf(denom[r]) * LN2;   // v_log_f32 is log2
    for (int i = threadIdx.x; i < N_BATCH; i += 256)
        a2 += pos[i];
    #pragma unroll
    for (int m = 1; m < 64; m <<= 1) {
        a1 += __shfl_xor(a1, m, 64);
        a2 += __shfl_xor(a2, m, 64);
    }
    __shared__ float r1[4], r2[4];
    int wv = threadIdx.x >> 6;
    if ((threadIdx.x & 63) == 0) { r1[wv] = a1; r2[wv] = a2; }
    __syncthreads();
    if (threadIdx.x == 0) {
        float s1 = r1[0] + r1[1] + r1[2] + r1[3];
        float s2 = r2[0] + r2[1] + r2[2] + r2[3];
        out[0] = (s1 - 2.0f * TINV * s2) / (float)M_ROWS;
    }
}

extern "C" void kernel_launch(void* const* d_in, const int* in_sizes, int n_in,
                              void* d_out, int out_size, void* d_ws, size_t ws_size,
                              hipStream_t stream)
{
    const float* emb_i = (const float*)d_in[0];
    const float* emb_j = (const float*)d_in[1];
    float* out = (float*)d_out;

    char*   ws    = (char*)d_ws;
    __bf16* zb    = (__bf16*)ws;                                   // 16 MB
    float*  denom = (float*)(ws + (size_t)M_ROWS * D_DIM * 2);     // 32 KB
    float*  pos   = denom + M_ROWS;                                // 16 KB

    hipLaunchKernelGGL(normalize_kernel, dim3(M_ROWS), dim3(256), 0, stream,
                       emb_i, emb_j, zb, denom);
    hipLaunchKernelGGL(pos_kernel, dim3(N_BATCH / 4), dim3(256), 0, stream,
                       emb_i, emb_j, pos);
    hipLaunchKernelGGL(simexp_kernel, dim3(64, 64), dim3(256), 0, stream,
                       zb, denom);
    hipLaunchKernelGGL(finalize_kernel, dim3(1), dim3(256), 0, stream,
                       denom, pos, out);
}

// Round 2
// 213.175 us; speedup vs baseline: 1.0117x; 1.0117x over previous
//
#include <hip/hip_runtime.h>
#include <hip/hip_bf16.h>
#include <stdint.h>

#define N_BATCH 4096
#define D_DIM   1024
#define M_ROWS  8192                     // 2N
#define TINV    2.0f                     // 1/temperature
#define EXP_SCALE 2.8853900817779268f    // log2(e)/t  (t=0.5)
#define LN2 0.6931471805599453f

typedef __bf16 bf16x8 __attribute__((ext_vector_type(8)));
typedef float  f32x4  __attribute__((ext_vector_type(4)));

__device__ __forceinline__ void load_lds16(const __bf16* g, __bf16* l) {
    __builtin_amdgcn_global_load_lds(
        (const __attribute__((address_space(1))) void*)g,
        (__attribute__((address_space(3))) void*)l, 16, 0, 0);
}

// ---- kernel 1: fused L2-normalize (bf16 Z out) + exact fp32 positives ----
// one block per pair i: handles emb_i[i] -> Z[i], emb_j[i] -> Z[i+N], pos[i]
__global__ __launch_bounds__(256) void norm_pos_kernel(
    const float* __restrict__ emb_i, const float* __restrict__ emb_j,
    __bf16* __restrict__ zb, float* __restrict__ pos, float* __restrict__ denom)
{
    int i = blockIdx.x;
    int t = threadIdx.x;
    float4 va = ((const float4*)(emb_i + (size_t)i * D_DIM))[t];
    float4 vb = ((const float4*)(emb_j + (size_t)i * D_DIM))[t];
    float ssa = va.x*va.x + va.y*va.y + va.z*va.z + va.w*va.w;
    float ssb = vb.x*vb.x + vb.y*vb.y + vb.z*vb.z + vb.w*vb.w;
    float dot = va.x*vb.x + va.y*vb.y + va.z*vb.z + va.w*vb.w;
    #pragma unroll
    for (int m = 1; m < 64; m <<= 1) {
        ssa += __shfl_xor(ssa, m, 64);
        ssb += __shfl_xor(ssb, m, 64);
        dot += __shfl_xor(dot, m, 64);
    }
    __shared__ float ra[4], rb[4], rd[4];
    int wv = t >> 6;
    if ((t & 63) == 0) { ra[wv] = ssa; rb[wv] = ssb; rd[wv] = dot; }
    __syncthreads();
    float SSA = ra[0] + ra[1] + ra[2] + ra[3];
    float SSB = rb[0] + rb[1] + rb[2] + rb[3];
    float na = fmaxf(sqrtf(SSA), 1e-12f);
    float nb = fmaxf(sqrtf(SSB), 1e-12f);
    float sa = 1.0f / na, sb = 1.0f / nb;
    union { __bf16 h[4]; uint2 u; } cv;
    cv.h[0] = (__bf16)(va.x * sa); cv.h[1] = (__bf16)(va.y * sa);
    cv.h[2] = (__bf16)(va.z * sa); cv.h[3] = (__bf16)(va.w * sa);
    *(uint2*)(zb + (size_t)i * D_DIM + t * 4) = cv.u;
    cv.h[0] = (__bf16)(vb.x * sb); cv.h[1] = (__bf16)(vb.y * sb);
    cv.h[2] = (__bf16)(vb.z * sb); cv.h[3] = (__bf16)(vb.w * sb);
    *(uint2*)(zb + (size_t)(i + N_BATCH) * D_DIM + t * 4) = cv.u;
    if (t == 0) {
        float DOT = rd[0] + rd[1] + rd[2] + rd[3];
        pos[i] = DOT / (na * nb);
        denom[i] = 0.0f;
        denom[i + N_BATCH] = 0.0f;
    }
}

// ---- kernel 2: fused sim = Z Z^T -> exp -> masked row/col sums -----------
// Block tile 256(M) x 128(N), BK=32. 4 waves, wave tile 128x64 (fm=8,fn=4).
// Upper-triangle cover: keep blocks with bx >= 2*by; per-element predicate
// c>r adds e into rowsum[r] AND colsum[c] -> every unordered pair counted
// exactly once into both endpoints, diagonal naturally excluded.
__global__ __launch_bounds__(256, 2) void simexp_kernel(
    const __bf16* __restrict__ Z, float* __restrict__ denom)
{
    int bx = blockIdx.x;        // col band, 128 wide, 0..63
    int by = blockIdx.y;        // row band, 256 tall, 0..31
    if (bx < 2 * by) return;    // fully below diagonal -> no c>r elements
    int tile_m = by * 256, tile_n = bx * 128;

    __shared__ __align__(16) __bf16 As[256 * 32];   // 16 KB
    __shared__ __align__(16) __bf16 Bs[128 * 32];   // 8 KB

    int t    = threadIdx.x;
    int wv   = t >> 6;
    int lane = t & 63;
    int wave_m = (wv >> 1) * 128;   // 2 waves in m
    int wave_n = (wv & 1) * 64;     // 2 waves in n
    int quad = lane >> 4;
    int l15  = lane & 15;

    f32x4 acc[8][4] = {};

    // staging: thread t loads 16B at row=(t>>2) (+64*j), col-octet=(t&3)
    int srow = t >> 2;
    int soct = (t & 3) * 8;
    const __bf16* gA = Z + (size_t)(tile_m + srow) * D_DIM + soct;
    const __bf16* gB = Z + (size_t)(tile_n + srow) * D_DIM + soct;

    for (int k0 = 0; k0 < D_DIM; k0 += 32) {
        __syncthreads();
        #pragma unroll
        for (int j = 0; j < 4; ++j)
            load_lds16(gA + (size_t)j * 64 * D_DIM + k0, As + j * 2048 + wv * 512);
        #pragma unroll
        for (int j = 0; j < 2; ++j)
            load_lds16(gB + (size_t)j * 64 * D_DIM + k0, Bs + j * 2048 + wv * 512);
        __syncthreads();

        bf16x8 af[8], bf[4];
        #pragma unroll
        for (int f = 0; f < 8; ++f)
            af[f] = *(const bf16x8*)&As[(wave_m + f * 16 + l15) * 32 + quad * 8];
        #pragma unroll
        for (int f = 0; f < 4; ++f)
            bf[f] = *(const bf16x8*)&Bs[(wave_n + f * 16 + l15) * 32 + quad * 8];

        #pragma unroll
        for (int fm = 0; fm < 8; ++fm)
            #pragma unroll
            for (int fn = 0; fn < 4; ++fn)
                acc[fm][fn] = __builtin_amdgcn_mfma_f32_16x16x32_bf16(
                    af[fm], bf[fn], acc[fm][fn], 0, 0, 0);
    }

    // epilogue: e = exp2(sim*log2(e)/t) only where c>r; row + col reductions
    int rbase = tile_m + wave_m + quad * 4;
    int cbase = tile_n + wave_n + l15;
    float colacc[4] = {0.f, 0.f, 0.f, 0.f};
    #pragma unroll
    for (int fm = 0; fm < 8; ++fm) {
        #pragma unroll
        for (int r = 0; r < 4; ++r) {
            int rg = rbase + fm * 16 + r;
            float rowacc = 0.f;
            #pragma unroll
            for (int fn = 0; fn < 4; ++fn) {
                int cg = cbase + fn * 16;
                float e = (cg > rg)
                    ? __builtin_amdgcn_exp2f(acc[fm][fn][r] * EXP_SCALE)
                    : 0.f;
                rowacc += e;
                colacc[fn] += e;
            }
            rowacc += __shfl_xor(rowacc, 1, 64);
            rowacc += __shfl_xor(rowacc, 2, 64);
            rowacc += __shfl_xor(rowacc, 4, 64);
            rowacc += __shfl_xor(rowacc, 8, 64);
            if (l15 == 0) atomicAdd(&denom[rg], rowacc);
        }
    }
    #pragma unroll
    for (int fn = 0; fn < 4; ++fn) {
        float s = colacc[fn];
        s += __shfl_xor(s, 16, 64);
        s += __shfl_xor(s, 32, 64);
        if (quad == 0) atomicAdd(&denom[cbase + fn * 16], s);
    }
}

// ---- kernel 3: loss = [sum log(denom) - (2/t) sum pos] / 2N --------------
__global__ __launch_bounds__(256) void finalize_kernel(
    const float* __restrict__ denom, const float* __restrict__ pos,
    float* __restrict__ out)
{
    float a1 = 0.f, a2 = 0.f;
    for (int r = threadIdx.x; r < M_ROWS; r += 256)
        a1 += __builtin_amdgcn_logf(denom[r]) * LN2;   // v_log_f32 is log2
    for (int i = threadIdx.x; i < N_BATCH; i += 256)
        a2 += pos[i];
    #pragma unroll
    for (int m = 1; m < 64; m <<= 1) {
        a1 += __shfl_xor(a1, m, 64);
        a2 += __shfl_xor(a2, m, 64);
    }
    __shared__ float r1[4], r2[4];
    int wv = threadIdx.x >> 6;
    if ((threadIdx.x & 63) == 0) { r1[wv] = a1; r2[wv] = a2; }
    __syncthreads();
    if (threadIdx.x == 0) {
        float s1 = r1[0] + r1[1] + r1[2] + r1[3];
        float s2 = r2[0] + r2[1] + r2[2] + r2[3];
        out[0] = (s1 - 2.0f * TINV * s2) / (float)M_ROWS;
    }
}

extern "C" void kernel_launch(void* const* d_in, const int* in_sizes, int n_in,
                              void* d_out, int out_size, void* d_ws, size_t ws_size,
                              hipStream_t stream)
{
    const float* emb_i = (const float*)d_in[0];
    const float* emb_j = (const float*)d_in[1];
    float* out = (float*)d_out;

    char*   ws    = (char*)d_ws;
    __bf16* zb    = (__bf16*)ws;                                   // 16 MB
    float*  denom = (float*)(ws + (size_t)M_ROWS * D_DIM * 2);     // 32 KB
    float*  pos   = denom + M_ROWS;                                // 16 KB

    hipLaunchKernelGGL(norm_pos_kernel, dim3(N_BATCH), dim3(256), 0, stream,
                       emb_i, emb_j, zb, pos, denom);
    hipLaunchKernelGGL(simexp_kernel, dim3(64, 32), dim3(256), 0, stream,
                       zb, denom);
    hipLaunchKernelGGL(finalize_kernel, dim3(1), dim3(256), 0, stream,
                       denom, pos, out);
}

// Round 3
// 195.562 us; speedup vs baseline: 1.1029x; 1.0901x over previous
//
#include <hip/hip_runtime.h>
#include <hip/hip_bf16.h>
#include <stdint.h>

#define N_BATCH 4096
#define D_DIM   1024
#define M_ROWS  8192                     // 2N
#define TINV    2.0f                     // 1/temperature
#define EXP_SCALE 2.8853900817779268f    // log2(e)/t  (t=0.5)
#define LN2 0.6931471805599453f

typedef __bf16 bf16x8 __attribute__((ext_vector_type(8)));
typedef float  f32x4  __attribute__((ext_vector_type(4)));

__device__ __forceinline__ void load_lds16(const __bf16* g, __bf16* l) {
    __builtin_amdgcn_global_load_lds(
        (const __attribute__((address_space(1))) void*)g,
        (__attribute__((address_space(3))) void*)l, 16, 0, 0);
}

// ---- kernel 1: fused L2-normalize (bf16 Z out) + exact fp32 positives ----
__global__ __launch_bounds__(256) void norm_pos_kernel(
    const float* __restrict__ emb_i, const float* __restrict__ emb_j,
    __bf16* __restrict__ zb, float* __restrict__ pos, float* __restrict__ denom)
{
    int i = blockIdx.x;
    int t = threadIdx.x;
    float4 va = ((const float4*)(emb_i + (size_t)i * D_DIM))[t];
    float4 vb = ((const float4*)(emb_j + (size_t)i * D_DIM))[t];
    float ssa = va.x*va.x + va.y*va.y + va.z*va.z + va.w*va.w;
    float ssb = vb.x*vb.x + vb.y*vb.y + vb.z*vb.z + vb.w*vb.w;
    float dot = va.x*vb.x + va.y*vb.y + va.z*vb.z + va.w*vb.w;
    #pragma unroll
    for (int m = 1; m < 64; m <<= 1) {
        ssa += __shfl_xor(ssa, m, 64);
        ssb += __shfl_xor(ssb, m, 64);
        dot += __shfl_xor(dot, m, 64);
    }
    __shared__ float ra[4], rb[4], rd[4];
    int wv = t >> 6;
    if ((t & 63) == 0) { ra[wv] = ssa; rb[wv] = ssb; rd[wv] = dot; }
    __syncthreads();
    float SSA = ra[0] + ra[1] + ra[2] + ra[3];
    float SSB = rb[0] + rb[1] + rb[2] + rb[3];
    float na = fmaxf(sqrtf(SSA), 1e-12f);
    float nb = fmaxf(sqrtf(SSB), 1e-12f);
    float sa = 1.0f / na, sb = 1.0f / nb;
    union { __bf16 h[4]; uint2 u; } cv;
    cv.h[0] = (__bf16)(va.x * sa); cv.h[1] = (__bf16)(va.y * sa);
    cv.h[2] = (__bf16)(va.z * sa); cv.h[3] = (__bf16)(va.w * sa);
    *(uint2*)(zb + (size_t)i * D_DIM + t * 4) = cv.u;
    cv.h[0] = (__bf16)(vb.x * sb); cv.h[1] = (__bf16)(vb.y * sb);
    cv.h[2] = (__bf16)(vb.z * sb); cv.h[3] = (__bf16)(vb.w * sb);
    *(uint2*)(zb + (size_t)(i + N_BATCH) * D_DIM + t * 4) = cv.u;
    if (t == 0) {
        float DOT = rd[0] + rd[1] + rd[2] + rd[3];
        pos[i] = DOT / (na * nb);
        denom[i] = 0.0f;
        denom[i + N_BATCH] = 0.0f;
    }
}

// ---- kernel 2: fused sim = Z Z^T -> exp -> masked row/col sums -----------
// 128x128 tile, BK=32, double-buffered LDS, ONE barrier per K-iter:
//   issue DMA(k+1 -> buf^1) ; ds_read+MFMA on buf ; barrier (drains DMA)
// Triangle cover: keep bx>=by; per-element predicate c>r adds e into
// rowsum[r] and colsum[c] -> each unordered pair counted exactly once.
__global__ __launch_bounds__(256, 3) void simexp_kernel(
    const __bf16* __restrict__ Z, float* __restrict__ denom)
{
    int bx = blockIdx.x;
    int by = blockIdx.y;
    if (bx < by) return;
    int tile_m = by * 128, tile_n = bx * 128;

    // [buf][A=0/B=1][128*32 bf16]  -> 32 KB total
    __shared__ __align__(16) __bf16 sh[2][2][128 * 32];

    int t    = threadIdx.x;
    int wv   = t >> 6;
    int lane = t & 63;
    int wave_m = (wv >> 1) * 64;
    int wave_n = (wv & 1) * 64;
    int quad = lane >> 4;
    int l15  = lane & 15;

    // staging: thread t loads 16B at row=(t>>2) (+64), col-octet=(t&3)
    int srow = t >> 2;
    int soct = (t & 3) * 8;
    const __bf16* gA = Z + (size_t)(tile_m + srow) * D_DIM + soct;
    const __bf16* gB = Z + (size_t)(tile_n + srow) * D_DIM + soct;

    f32x4 acc[4][4] = {};

    // prologue: stage k=0 into buf 0, drain once
    load_lds16(gA,                  &sh[0][0][wv * 512]);
    load_lds16(gA + 64 * D_DIM,     &sh[0][0][2048 + wv * 512]);
    load_lds16(gB,                  &sh[0][1][wv * 512]);
    load_lds16(gB + 64 * D_DIM,     &sh[0][1][2048 + wv * 512]);
    __syncthreads();

    for (int it = 0; it < 32; ++it) {
        int p = it & 1;
        if (it + 1 < 32) {
            int k0 = (it + 1) * 32;
            load_lds16(gA + k0,              &sh[p ^ 1][0][wv * 512]);
            load_lds16(gA + 64 * D_DIM + k0, &sh[p ^ 1][0][2048 + wv * 512]);
            load_lds16(gB + k0,              &sh[p ^ 1][1][wv * 512]);
            load_lds16(gB + 64 * D_DIM + k0, &sh[p ^ 1][1][2048 + wv * 512]);
        }
        bf16x8 af[4], bf[4];
        #pragma unroll
        for (int f = 0; f < 4; ++f) {
            af[f] = *(const bf16x8*)&sh[p][0][(wave_m + f * 16 + l15) * 32 + quad * 8];
            bf[f] = *(const bf16x8*)&sh[p][1][(wave_n + f * 16 + l15) * 32 + quad * 8];
        }
        #pragma unroll
        for (int fm = 0; fm < 4; ++fm)
            #pragma unroll
            for (int fn = 0; fn < 4; ++fn)
                acc[fm][fn] = __builtin_amdgcn_mfma_f32_16x16x32_bf16(
                    af[fm], bf[fn], acc[fm][fn], 0, 0, 0);
        __syncthreads();   // consumers done with sh[p]; drains DMA(it+1)
    }

    // epilogue: e = exp2(sim*log2(e)/t) only where c>r; row + col reductions
    int rbase = tile_m + wave_m + quad * 4;
    int cbase = tile_n + wave_n + l15;
    float colacc[4] = {0.f, 0.f, 0.f, 0.f};
    #pragma unroll
    for (int fm = 0; fm < 4; ++fm) {
        #pragma unroll
        for (int r = 0; r < 4; ++r) {
            int rg = rbase + fm * 16 + r;
            float rowacc = 0.f;
            #pragma unroll
            for (int fn = 0; fn < 4; ++fn) {
                int cg = cbase + fn * 16;
                float e = (cg > rg)
                    ? __builtin_amdgcn_exp2f(acc[fm][fn][r] * EXP_SCALE)
                    : 0.f;
                rowacc += e;
                colacc[fn] += e;
            }
            rowacc += __shfl_xor(rowacc, 1, 64);
            rowacc += __shfl_xor(rowacc, 2, 64);
            rowacc += __shfl_xor(rowacc, 4, 64);
            rowacc += __shfl_xor(rowacc, 8, 64);
            if (l15 == 0) atomicAdd(&denom[rg], rowacc);
        }
    }
    #pragma unroll
    for (int fn = 0; fn < 4; ++fn) {
        float s = colacc[fn];
        s += __shfl_xor(s, 16, 64);
        s += __shfl_xor(s, 32, 64);
        if (quad == 0) atomicAdd(&denom[cbase + fn * 16], s);
    }
}

// ---- kernel 3: loss = [sum log(denom) - (2/t) sum pos] / 2N --------------
__global__ __launch_bounds__(256) void finalize_kernel(
    const float* __restrict__ denom, const float* __restrict__ pos,
    float* __restrict__ out)
{
    float a1 = 0.f, a2 = 0.f;
    for (int r = threadIdx.x; r < M_ROWS; r += 256)
        a1 += __builtin_amdgcn_logf(denom[r]) * LN2;   // v_log_f32 is log2
    for (int i = threadIdx.x; i < N_BATCH; i += 256)
        a2 += pos[i];
    #pragma unroll
    for (int m = 1; m < 64; m <<= 1) {
        a1 += __shfl_xor(a1, m, 64);
        a2 += __shfl_xor(a2, m, 64);
    }
    __shared__ float r1[4], r2[4];
    int wv = threadIdx.x >> 6;
    if ((threadIdx.x & 63) == 0) { r1[wv] = a1; r2[wv] = a2; }
    __syncthreads();
    if (threadIdx.x == 0) {
        float s1 = r1[0] + r1[1] + r1[2] + r1[3];
        float s2 = r2[0] + r2[1] + r2[2] + r2[3];
        out[0] = (s1 - 2.0f * TINV * s2) / (float)M_ROWS;
    }
}

extern "C" void kernel_launch(void* const* d_in, const int* in_sizes, int n_in,
                              void* d_out, int out_size, void* d_ws, size_t ws_size,
                              hipStream_t stream)
{
    const float* emb_i = (const float*)d_in[0];
    const float* emb_j = (const float*)d_in[1];
    float* out = (float*)d_out;

    char*   ws    = (char*)d_ws;
    __bf16* zb    = (__bf16*)ws;                                   // 16 MB
    float*  denom = (float*)(ws + (size_t)M_ROWS * D_DIM * 2);     // 32 KB
    float*  pos   = denom + M_ROWS;                                // 16 KB

    hipLaunchKernelGGL(norm_pos_kernel, dim3(N_BATCH), dim3(256), 0, stream,
                       emb_i, emb_j, zb, pos, denom);
    hipLaunchKernelGGL(simexp_kernel, dim3(64, 64), dim3(256), 0, stream,
                       zb, denom);
    hipLaunchKernelGGL(finalize_kernel, dim3(1), dim3(256), 0, stream,
                       denom, pos, out);
}